// Round 1
// baseline (32.368 us; speedup 1.0000x reference)
//
#include <hip/hip_runtime.h>

#define MARGIN 0.5f
#define EPS    1e-6f
#define BN     8192          // B
#define TPB    256
#define NBLK   1024          // 1024 blocks * 256 thr = 262144 threads = 32 rows-per-thread-stride
// total pairs = BN*BN = 67,108,864 ; pairs per thread = 256

// Kernel 1: each thread owns column j = tid & (BN-1) (loop-invariant regs),
// sweeps rows i = (tid>>13) + 32*k, k=0..255 (wave-uniform -> broadcast loads).
__global__ __launch_bounds__(TPB) void pairloss_partial(
    const float* __restrict__ preds,
    const float* __restrict__ targets,
    const int*   __restrict__ pdb,
    double* __restrict__ psum,
    unsigned long long* __restrict__ pcnt)
{
    const int tid = blockIdx.x * TPB + threadIdx.x;   // 0..262143
    const int j   = tid & (BN - 1);
    const int ib  = tid >> 13;                        // 0..31

    const float pj = preds[j];
    const float tj = targets[j] + EPS;
    const int   gj = pdb[j];

    float sum = 0.0f;
    int   cnt = 0;

    #pragma unroll 8
    for (int k = 0; k < 256; ++k) {
        const int i  = ib + (k << 5);
        const float ti = targets[i];     // wave-uniform
        const int   gi = pdb[i];         // wave-uniform
        const float pi = preds[i];       // wave-uniform
        const bool valid = (gi == gj) && (ti > tj);   // i==j can never pass (t > t+eps false)
        const float h = fmaxf(MARGIN - (pi - pj), 0.0f);
        sum += valid ? h : 0.0f;
        cnt += valid ? 1 : 0;
    }

    // wave (64-lane) reduce
    #pragma unroll
    for (int off = 32; off > 0; off >>= 1) {
        sum += __shfl_down(sum, off);
        cnt += __shfl_down(cnt, off);
    }

    __shared__ float ws[TPB / 64];
    __shared__ int   wc[TPB / 64];
    const int lane = threadIdx.x & 63;
    const int wv   = threadIdx.x >> 6;
    if (lane == 0) { ws[wv] = sum; wc[wv] = cnt; }
    __syncthreads();
    if (threadIdx.x == 0) {
        float s = 0.0f; int c = 0;
        #pragma unroll
        for (int w = 0; w < TPB / 64; ++w) { s += ws[w]; c += wc[w]; }
        psum[blockIdx.x] = (double)s;
        pcnt[blockIdx.x] = (unsigned long long)c;
    }
}

// Kernel 2: single block of 1024 threads reduces the NBLK partials.
__global__ __launch_bounds__(1024) void pairloss_finalize(
    const double* __restrict__ psum,
    const unsigned long long* __restrict__ pcnt,
    float* __restrict__ out)
{
    const int t = threadIdx.x;            // 0..1023, NBLK == 1024
    double s = psum[t];
    unsigned long long c = pcnt[t];

    #pragma unroll
    for (int off = 32; off > 0; off >>= 1) {
        s += __shfl_down(s, off);
        c += __shfl_down(c, off);
    }

    __shared__ double ss[16];
    __shared__ unsigned long long cc[16];
    const int lane = t & 63;
    const int wv   = t >> 6;
    if (lane == 0) { ss[wv] = s; cc[wv] = c; }
    __syncthreads();
    if (t == 0) {
        double S = 0.0; unsigned long long C = 0;
        #pragma unroll
        for (int w = 0; w < 16; ++w) { S += ss[w]; C += cc[w]; }
        const double denom = (double)(C > 0 ? C : 1ull);
        out[0] = (C == 0) ? 0.0f : (float)(S / denom);
    }
}

extern "C" void kernel_launch(void* const* d_in, const int* in_sizes, int n_in,
                              void* d_out, int out_size, void* d_ws, size_t ws_size,
                              hipStream_t stream)
{
    const float* preds   = (const float*)d_in[0];
    const float* targets = (const float*)d_in[1];
    const int*   pdb     = (const int*)d_in[2];
    float* out = (float*)d_out;

    double* psum = (double*)d_ws;                       // NBLK doubles = 8 KB
    unsigned long long* pcnt = (unsigned long long*)(psum + NBLK);  // 8 KB more

    pairloss_partial<<<NBLK, TPB, 0, stream>>>(preds, targets, pdb, psum, pcnt);
    pairloss_finalize<<<1, 1024, 0, stream>>>(psum, pcnt, out);
}